// Round 1
// baseline (96.889 us; speedup 1.0000x reference)
//
#include <hip/hip_runtime.h>
#include <hip/hip_bf16.h>

// out[b] = adj @ (x[b] @ W) + bias ; B=64, N=4096, F_IN=F_OUT=32
// R16: DEPTH-2 COUNTED-VMCNT PIPELINE (T3/T4) on the proven R15 wave geometry.
//   Block 128Mx256N, 8 waves = 2wr x 2nc x 2ks; wave tile 64x128 (0.0469 B/MAC,
//   LDS-BW cap ~81% MfmaUtil). Ring-3 LDS (3x48KB=144KB) -> stage t+2 while
//   computing t; s_waitcnt vmcnt(12) (never 0 in main loop) + raw s_barrier
//   replaces __syncthreads' vmcnt(0) drain (the measured 46%-util stall).
//   Grid 256 = 1 blk/CU, 8 waves/CU (same TLP as R15's 2x4-wave blocks).
//   Split-K merge: ks=1 waves park acc (4x32KB) in the dead ring LDS.
// Prep unchanged (HBM-roofline-ish ~30us). ws>=50.4MB proven; half-split fallback.

#define B_SZ 64
#define N_SZ 4096
#define NT 64
#define STG 49152

typedef __attribute__((ext_vector_type(8))) short bf16x8;
typedef __attribute__((ext_vector_type(4))) float f32x4;
typedef __attribute__((ext_vector_type(8))) unsigned short u16x8;

__device__ __forceinline__ unsigned short f2bf(float f) {
  unsigned int u = __float_as_uint(f);
  u += 0x7fffu + ((u >> 16) & 1u);
  return (unsigned short)(u >> 16);
}

__device__ __forceinline__ void support_body(const float* __restrict__ x,
                                             const float* __restrict__ W,
                                             unsigned short* __restrict__ St,
                                             int gid) {
  const int m = gid & (N_SZ - 1);
  const int b = gid >> 12;
  const float4* xr = (const float4*)(x + (size_t)gid * 32);
  float xv[32];
#pragma unroll
  for (int i = 0; i < 8; ++i) {
    float4 v = xr[i];
    xv[4 * i + 0] = v.x; xv[4 * i + 1] = v.y;
    xv[4 * i + 2] = v.z; xv[4 * i + 3] = v.w;
  }
  const size_t obase = ((size_t)b * 32) * (size_t)N_SZ + m;
#pragma unroll
  for (int o = 0; o < 32; ++o) {
    float acc = 0.f;
#pragma unroll
    for (int f = 0; f < 32; ++f) acc = fmaf(xv[f], W[f * 32 + o], acc);
    St[obase + (size_t)o * N_SZ] = f2bf(acc);
  }
}

__device__ __forceinline__ void cvt_body(const float* __restrict__ a,
                                         unsigned short* __restrict__ o,
                                         size_t idx8) {
  const size_t i = idx8 * 8;
  const float4* p = (const float4*)(a + i);
  float4 v0 = p[0], v1 = p[1];
  u16x8 r;
  r[0] = f2bf(v0.x); r[1] = f2bf(v0.y); r[2] = f2bf(v0.z); r[3] = f2bf(v0.w);
  r[4] = f2bf(v1.x); r[5] = f2bf(v1.y); r[6] = f2bf(v1.z); r[7] = f2bf(v1.w);
  *(u16x8*)(o + i) = r;
}

// ---------------- prep: fused full-adj cvt + support (full path) ------------
__global__ __launch_bounds__(256) void k_prep(const float* __restrict__ x,
                                              const float* __restrict__ adj,
                                              const float* __restrict__ W,
                                              unsigned short* __restrict__ St,
                                              unsigned short* __restrict__ adjB) {
  const int bid = blockIdx.x;
  const int t = threadIdx.x;
  if (bid < 8192) cvt_body(adj, adjB, (size_t)bid * 256 + t);
  else support_body(x, W, St, (bid - 8192) * 256 + t);
}

// fallback-path kernels
__global__ __launch_bounds__(256) void k_support(const float* __restrict__ x,
                                                 const float* __restrict__ W,
                                                 unsigned short* __restrict__ St) {
  support_body(x, W, St, blockIdx.x * 256 + threadIdx.x);
}
__global__ __launch_bounds__(256) void k_cvt(const float* __restrict__ a,
                                             unsigned short* __restrict__ o) {
  cvt_body(a, o, (size_t)blockIdx.x * 256 + threadIdx.x);
}

// -- GEMM: 128Mx256N, 8 waves (2M x 2N x 2KS, wave 64x128), ring-3, 1 blk/CU -
#define GLOAD16(gp, lp)                                                        \
  __builtin_amdgcn_global_load_lds(                                            \
      (const __attribute__((address_space(1))) void*)(gp),                     \
      (__attribute__((address_space(3))) void*)(lp), 16, 0, 0)
#define PRIO1() __builtin_amdgcn_s_setprio(1)
#define PRIO0() __builtin_amdgcn_s_setprio(0)
#define VMW(N_) asm volatile("s_waitcnt vmcnt(" #N_ ")" ::: "memory")
#define LGKM0() asm volatile("s_waitcnt lgkmcnt(0)" ::: "memory")
#define BARR() asm volatile("s_barrier" ::: "memory")
#define SCHED0() __builtin_amdgcn_sched_barrier(0)

__global__ __launch_bounds__(512, 2) void k_gemm8(const unsigned short* __restrict__ Ab,
                                                  const unsigned short* __restrict__ Bm,
                                                  const float* __restrict__ bias,
                                                  float* __restrict__ out,
                                                  int nbm, int rowoff) {
  __shared__ __attribute__((aligned(16))) char SM[147456];  // 3 x 48KB ring
  const int t = threadIdx.x;
  const int wg = blockIdx.x;
  const int xcd = wg & 7;
  const int c = wg >> 3;
  const int bm0 = (xcd * nbm + (c >> 3)) << 7;  // 128-row panel
  const int bn0 = (c & 7) << 8;                 // 256-col panel
  const int lane = t & 63;
  const int wid = t >> 6;          // 0..7
  const int wr = wid & 1;          // M-half (64 rows)
  const int nc = (wid >> 1) & 1;   // N-half (128 cols)
  const int ks = wid >> 2;         // split-K team: kk-half of BK=64

  f32x4 acc[4][8];
#pragma unroll
  for (int i = 0; i < 4; ++i)
#pragma unroll
    for (int j = 0; j < 8; ++j) acc[i][j] = (f32x4){0.f, 0.f, 0.f, 0.f};

  // staging: 6 gloads/stage (A 2 + B 4), each 512thr x 16B = 8KB = 64 rows
  const int srow = t >> 3;   // 0..63
  const int as = t & 7;
  const int swz = (as ^ (srow & 7)) << 4;  // inverse-swizzled source (rule #21)
  const size_t a_s0 = ((size_t)(bm0 + srow) << 13) + (size_t)swz;
  const size_t b_s0 = ((size_t)(bn0 + srow) << 13) + (size_t)swz;
  const int t16 = t * 16;
  const char* A8 = (const char*)Ab;
  const char* B8 = (const char*)Bm;

#define STAGE(KT_, LOFF_)                                                      \
  do {                                                                         \
    const size_t kb = (size_t)(KT_) << 7;                                      \
    GLOAD16(A8 + a_s0 + kb,           SM + (LOFF_) + t16);                     \
    GLOAD16(A8 + a_s0 + 524288 + kb,  SM + (LOFF_) + 8192 + t16);              \
    GLOAD16(B8 + b_s0 + kb,           SM + (LOFF_) + 16384 + t16);             \
    GLOAD16(B8 + b_s0 + 524288 + kb,  SM + (LOFF_) + 24576 + t16);             \
    GLOAD16(B8 + b_s0 + 1048576 + kb, SM + (LOFF_) + 32768 + t16);             \
    GLOAD16(B8 + b_s0 + 1572864 + kb, SM + (LOFF_) + 40960 + t16);             \
  } while (0)

  // fragment LDS byte offsets (kk = ks per team; XOR swizzle, proven)
  const int cbase = (ks * 64 + ((lane >> 4) << 4)) ^ ((lane & 7) << 4);
  int aoff[4], boff[8];
#pragma unroll
  for (int mi = 0; mi < 4; ++mi)
    aoff[mi] = (wr * 64 + mi * 16 + (lane & 15)) * 128 + cbase;
#pragma unroll
  for (int ni = 0; ni < 8; ++ni)
    boff[ni] = 16384 + (nc * 128 + ni * 16 + (lane & 15)) * 128 + cbase;

  // reads tile CUR_, lgkm-drains BEFORE the trailing barrier (WAR ledger),
  // then MFMAs after it so next iter's STAGE overlaps the matrix pipe.
#define FRAG_MFMA(CUROFF_)                                                     \
  do {                                                                         \
    bf16x8 a[4], b[8];                                                         \
    _Pragma("unroll") for (int mi = 0; mi < 4; ++mi)                           \
        a[mi] = *(const bf16x8*)(SM + (CUROFF_) + aoff[mi]);                   \
    _Pragma("unroll") for (int ni = 0; ni < 8; ++ni)                           \
        b[ni] = *(const bf16x8*)(SM + (CUROFF_) + boff[ni]);                   \
    LGKM0();                                                                   \
    SCHED0();                                                                  \
    BARR();                                                                    \
    PRIO1();                                                                   \
    _Pragma("unroll") for (int mi = 0; mi < 4; ++mi)                           \
        _Pragma("unroll") for (int ni = 0; ni < 8; ++ni)                       \
            acc[mi][ni] = __builtin_amdgcn_mfma_f32_16x16x32_bf16(             \
                a[mi], b[ni], acc[mi][ni], 0, 0, 0);                           \
    PRIO0();                                                                   \
  } while (0)

  // full iter: stage t+2, wait depth-2 (12 = 2 stages x 6 loads), compute t
#define ITER(T_, CUR_, NXT_)                                                   \
  do {                                                                         \
    STAGE((T_) + 2, (NXT_) * STG);                                             \
    VMW(12);                                                                   \
    BARR();                                                                    \
    FRAG_MFMA((CUR_) * STG);                                                   \
  } while (0)

  // prologue: tiles 0,1 into bufs 0,1
  STAGE(0, 0);
  STAGE(1, STG);

  for (int t0 = 0; t0 < 60; t0 += 3) {   // t = 0..59, ring phase static
    ITER(t0 + 0, 0, 2);
    ITER(t0 + 1, 1, 0);
    ITER(t0 + 2, 2, 1);
  }
  ITER(60, 0, 2);
  ITER(61, 1, 0);
  // peeled tails (no stage): t=62 in buf2 (one stage in flight), t=63 in buf0
  VMW(6);
  BARR();
  FRAG_MFMA(2 * STG);
  VMW(0);
  BARR();
  FRAG_MFMA(0 * STG);

  // ------- split-K merge through LDS (ring is dead now; 4 x 32KB regions) ---
  if (ks == 1) {
    char* mb = SM + ((wid & 3) << 15);
#pragma unroll
    for (int mi = 0; mi < 4; ++mi)
#pragma unroll
      for (int ni = 0; ni < 8; ++ni)
        *(f32x4*)(mb + (((mi * 8 + ni) << 6) + lane) * 16) = acc[mi][ni];
  }
  __syncthreads();
  if (ks == 0) {
    char* mb = SM + ((wid & 3) << 15);
#pragma unroll
    for (int mi = 0; mi < 4; ++mi)
#pragma unroll
      for (int ni = 0; ni < 8; ++ni)
        acc[mi][ni] += *(const f32x4*)(mb + (((mi * 8 + ni) << 6) + lane) * 16);
    // ---- epilogue: C/D layout col=lane&15, row=(lane>>4)*4+q (proven) ----
    const float blo = bias[lane & 15];
    const float bhi = bias[(lane & 15) + 16];
#pragma unroll
    for (int mi = 0; mi < 4; ++mi) {
#pragma unroll
      for (int ni = 0; ni < 8; ++ni) {
        const float badd = (ni & 1) ? bhi : blo;
#pragma unroll
        for (int q = 0; q < 4; ++q) {
          const int n = rowoff + bm0 + wr * 64 + mi * 16 + ((lane >> 4) << 2) + q;
          const int cidx = bn0 + nc * 128 + ni * 16 + (lane & 15);
          const int bb = cidx >> 5;
          const int o = cidx & 31;
          out[(((size_t)bb << 12) + n) * 32 + o] = acc[mi][ni][q] + badd;
        }
      }
    }
  }
}

extern "C" void kernel_launch(void* const* d_in, const int* in_sizes, int n_in,
                              void* d_out, int out_size, void* d_ws, size_t ws_size,
                              hipStream_t stream) {
  const float* x = (const float*)d_in[0];
  const float* adj = (const float*)d_in[1];
  const float* W = (const float*)d_in[2];
  const float* bias = (const float*)d_in[3];
  float* out = (float*)d_out;

  const size_t ST_B = (size_t)2048 * 4096 * 2;      // 16,777,216
  const size_t ADJ_FULL = (size_t)4096 * 4096 * 2;  // 33,554,432

  unsigned short* St = (unsigned short*)d_ws;

  if (ws_size >= ST_B + ADJ_FULL) {
    // full path: fused prep + one GEMM (grid 256 = 1 blk/CU, 8 waves)
    unsigned short* adjB = St + (ST_B / 2);
    hipLaunchKernelGGL(k_prep, dim3(9216), dim3(256), 0, stream, x, adj, W, St,
                       adjB);
    hipLaunchKernelGGL(k_gemm8, dim3(256), dim3(512), 0, stream, adjB, St, bias,
                       out, 4, 0);
  } else {
    // fallback half-split (not expected to run): one 2048-row panel reused
    unsigned short* adjH = St + (ST_B / 2);
    hipLaunchKernelGGL(k_support, dim3((B_SZ * N_SZ) / 256), dim3(256), 0,
                       stream, x, W, St);
    hipLaunchKernelGGL(k_cvt, dim3((2048 * 4096) / 2048), dim3(256), 0, stream,
                       adj, adjH);
    hipLaunchKernelGGL(k_gemm8, dim3(128), dim3(512), 0, stream, adjH, St, bias,
                       out, 2, 0);
    hipLaunchKernelGGL(k_cvt, dim3((2048 * 4096) / 2048), dim3(256), 0, stream,
                       adj + (size_t)2048 * 4096, adjH);
    hipLaunchKernelGGL(k_gemm8, dim3(128), dim3(512), 0, stream, adjH, St, bias,
                       out, 2, 2048);
  }
}

// Round 2
// 93.439 us; speedup vs baseline: 1.0369x; 1.0369x over previous
//
#include <hip/hip_runtime.h>
#include <hip/hip_bf16.h>

// out[b] = adj @ (x[b] @ W) + bias ; B=64, N=4096, F_IN=F_OUT=32
// R17: R15 structure (proven 61.4us GEMM) + L2-FITTING XCD REGION SWIZZLE.
//   Post-mortem R16: counted-vmcnt pipeline regressed (39% MfmaUtil) - the
//   2-barrier lockstep alternated LDS/MFMA pipes. Reverted.
//   New theory: step time 2287cyc vs 1030cyc MFMA floor; binding resource is
//   staging BW from BEYOND L2 (~1GB panel traffic @ ~17TB/s = L3 wall; old
//   swizzle gave each XCD a 512x2048 region = 20MB working set >> 4MB L2).
//   Fix: each XCD owns a 1024x1024 C-region = its 64 co-resident blocks
//   (8x8 tiles); instantaneous working set ~1MB -> L2-served staging,
//   beyond-L2 traffic 1GB -> ~128MB first-touch.
//   Block 128^2, 4 waves = 2 M-halves (wr) x 2 split-K teams (ks);
//   wave tile 64x128; acc[4][8]; dbuf 64KB; 2 blk/CU; single-sync loop
//   {STAGE(t+1)->other | 12 frag reads | 32 MFMA | sync} (R14/R15-proven).
// Prep at HBM roofline (~33us). ws>=50.4MB proven (R10); half-split fallback.

#define B_SZ 64
#define N_SZ 4096
#define NT 64

typedef __attribute__((ext_vector_type(8))) short bf16x8;
typedef __attribute__((ext_vector_type(4))) float f32x4;
typedef __attribute__((ext_vector_type(8))) unsigned short u16x8;

__device__ __forceinline__ unsigned short f2bf(float f) {
  unsigned int u = __float_as_uint(f);
  u += 0x7fffu + ((u >> 16) & 1u);
  return (unsigned short)(u >> 16);
}

__device__ __forceinline__ void support_body(const float* __restrict__ x,
                                             const float* __restrict__ W,
                                             unsigned short* __restrict__ St,
                                             int gid) {
  const int m = gid & (N_SZ - 1);
  const int b = gid >> 12;
  const float4* xr = (const float4*)(x + (size_t)gid * 32);
  float xv[32];
#pragma unroll
  for (int i = 0; i < 8; ++i) {
    float4 v = xr[i];
    xv[4 * i + 0] = v.x; xv[4 * i + 1] = v.y;
    xv[4 * i + 2] = v.z; xv[4 * i + 3] = v.w;
  }
  const size_t obase = ((size_t)b * 32) * (size_t)N_SZ + m;
#pragma unroll
  for (int o = 0; o < 32; ++o) {
    float acc = 0.f;
#pragma unroll
    for (int f = 0; f < 32; ++f) acc = fmaf(xv[f], W[f * 32 + o], acc);
    St[obase + (size_t)o * N_SZ] = f2bf(acc);
  }
}

__device__ __forceinline__ void cvt_body(const float* __restrict__ a,
                                         unsigned short* __restrict__ o,
                                         size_t idx8) {
  const size_t i = idx8 * 8;
  const float4* p = (const float4*)(a + i);
  float4 v0 = p[0], v1 = p[1];
  u16x8 r;
  r[0] = f2bf(v0.x); r[1] = f2bf(v0.y); r[2] = f2bf(v0.z); r[3] = f2bf(v0.w);
  r[4] = f2bf(v1.x); r[5] = f2bf(v1.y); r[6] = f2bf(v1.z); r[7] = f2bf(v1.w);
  *(u16x8*)(o + i) = r;
}

// ---------------- prep: fused full-adj cvt + support (full path) ------------
__global__ __launch_bounds__(256) void k_prep(const float* __restrict__ x,
                                              const float* __restrict__ adj,
                                              const float* __restrict__ W,
                                              unsigned short* __restrict__ St,
                                              unsigned short* __restrict__ adjB) {
  const int bid = blockIdx.x;
  const int t = threadIdx.x;
  if (bid < 8192) cvt_body(adj, adjB, (size_t)bid * 256 + t);
  else support_body(x, W, St, (bid - 8192) * 256 + t);
}

// fallback-path kernels
__global__ __launch_bounds__(256) void k_support(const float* __restrict__ x,
                                                 const float* __restrict__ W,
                                                 unsigned short* __restrict__ St) {
  support_body(x, W, St, blockIdx.x * 256 + threadIdx.x);
}
__global__ __launch_bounds__(256) void k_cvt(const float* __restrict__ a,
                                             unsigned short* __restrict__ o) {
  cvt_body(a, o, (size_t)blockIdx.x * 256 + threadIdx.x);
}

// -- GEMM: 128x128, 4 waves (2M x 2KS, wave 64x128), dbuf 64KB, 2 blk/CU -----
#define GLOAD16(gp, lp)                                                        \
  __builtin_amdgcn_global_load_lds(                                            \
      (const __attribute__((address_space(1))) void*)(gp),                     \
      (__attribute__((address_space(3))) void*)(lp), 16, 0, 0)
#define PRIO1() __builtin_amdgcn_s_setprio(1)
#define PRIO0() __builtin_amdgcn_s_setprio(0)

__global__ __launch_bounds__(256, 2) void k_gemm6(const unsigned short* __restrict__ Ab,
                                                  const unsigned short* __restrict__ Bm,
                                                  const float* __restrict__ bias,
                                                  float* __restrict__ out,
                                                  int nbm, int rowoff) {
  __shared__ __attribute__((aligned(16))) char SM[65536];
  char* Lc = SM;            // current tile buf: [A 16KB][B 16KB]
  char* Lo = SM + 32768;    // other buf
  const int t = threadIdx.x;
  const int wg = blockIdx.x;
  const int xcd = wg & 7;
  const int idx = wg >> 3;
  int bm0, bn0;
  if (nbm == 4) {
    // full path: XCD region = 1024x1024 (rm = xcd>>1, rn = xcd&1), 8x8 tiles.
    // 64 blocks/XCD co-resident share an L2-sized working set (~1MB/DK=256).
    bm0 = ((xcd >> 1) << 10) + ((idx >> 3) << 7);
    bn0 = ((xcd & 1) << 10) + ((idx & 7) << 7);
  } else {
    // fallback half-split path: old mapping (2048-row panel, 16 n-tiles)
    bm0 = (xcd * nbm + (idx >> 4)) << 7;
    bn0 = (idx & 15) << 7;
  }
  const int lane = t & 63;
  const int wid = t >> 6;          // 0..3
  const int wr = wid & 1;          // M-half (64 rows)
  const int ks = wid >> 1;         // split-K team: kk-half of BK=64

  f32x4 acc[4][8];
#pragma unroll
  for (int i = 0; i < 4; ++i)
#pragma unroll
    for (int j = 0; j < 8; ++j) acc[i][j] = (f32x4){0.f, 0.f, 0.f, 0.f};

  // staging: 8 gloads/tile (A 4 + B 4), each 256thr x 16B = 4KB = 32 rows
  const int srow = t >> 3;   // 0..31
  const int as = t & 7;
  const int swz = (as ^ (srow & 7)) << 4;  // inverse-swizzled source (rule #21)
  const size_t a_s0 = ((size_t)(bm0 + srow) << 13) + (size_t)swz;
  const size_t b_s0 = ((size_t)(bn0 + srow) << 13) + (size_t)swz;
  const int t16 = t * 16;
  const char* A8 = (const char*)Ab;
  const char* B8 = (const char*)Bm;

#define STAGE(KT_, Ld)                                                         \
  do {                                                                         \
    const size_t kb = (size_t)(KT_) << 7;                                      \
    GLOAD16(A8 + a_s0 + kb,          (Ld) + t16);                              \
    GLOAD16(A8 + a_s0 + 262144 + kb, (Ld) + 4096 + t16);                       \
    GLOAD16(A8 + a_s0 + 524288 + kb, (Ld) + 8192 + t16);                       \
    GLOAD16(A8 + a_s0 + 786432 + kb, (Ld) + 12288 + t16);                      \
    GLOAD16(B8 + b_s0 + kb,          (Ld) + 16384 + t16);                      \
    GLOAD16(B8 + b_s0 + 262144 + kb, (Ld) + 20480 + t16);                      \
    GLOAD16(B8 + b_s0 + 524288 + kb, (Ld) + 24576 + t16);                      \
    GLOAD16(B8 + b_s0 + 786432 + kb, (Ld) + 28672 + t16);                      \
  } while (0)

  // fragment LDS byte offsets (kk = ks per team; XOR swizzle, R10-proven)
  const int cbase = (ks * 64 + ((lane >> 4) << 4)) ^ ((lane & 7) << 4);
  int aoff[4], boff[8];
#pragma unroll
  for (int mi = 0; mi < 4; ++mi)
    aoff[mi] = (wr * 64 + mi * 16 + (lane & 15)) * 128 + cbase;
#pragma unroll
  for (int ni = 0; ni < 8; ++ni)
    boff[ni] = 16384 + (ni * 16 + (lane & 15)) * 128 + cbase;

  // prologue: tile 0 into buf0
  STAGE(0, Lc);
  __syncthreads();  // drains the 8 DMA loads

  for (int kt = 0; kt < NT; ++kt) {
    // 1) issue next tile's DMA first (max latency cover before the sync)
    if (kt + 1 < NT) STAGE(kt + 1, Lo);
    // 2) team frag reads (A 4 + B 8 = 12 ds_read_b128)
    bf16x8 a[4], b[8];
#pragma unroll
    for (int mi = 0; mi < 4; ++mi) a[mi] = *(const bf16x8*)(Lc + aoff[mi]);
#pragma unroll
    for (int ni = 0; ni < 8; ++ni) b[ni] = *(const bf16x8*)(Lc + boff[ni]);
    // 3) 32 MFMA (team's kk-half, 64x128 wave tile)
    PRIO1();
#pragma unroll
    for (int mi = 0; mi < 4; ++mi)
#pragma unroll
      for (int ni = 0; ni < 8; ++ni)
        acc[mi][ni] = __builtin_amdgcn_mfma_f32_16x16x32_bf16(
            a[mi], b[ni], acc[mi][ni], 0, 0, 0);
    PRIO0();
    // 4) barrier (drains DMA; covered by sibling block / other waves)
    __syncthreads();
    { char* tp_ = Lc; Lc = Lo; Lo = tp_; }
  }

  // ------- split-K merge through LDS (dbuf is dead now; 32KB per ks1-wave) --
  if (ks == 1) {
    char* mb = SM + (wr << 15);
#pragma unroll
    for (int mi = 0; mi < 4; ++mi)
#pragma unroll
      for (int ni = 0; ni < 8; ++ni)
        *(f32x4*)(mb + (((mi * 8 + ni) << 6) + lane) * 16) = acc[mi][ni];
  }
  __syncthreads();
  if (ks == 0) {
    char* mb = SM + (wr << 15);
#pragma unroll
    for (int mi = 0; mi < 4; ++mi)
#pragma unroll
      for (int ni = 0; ni < 8; ++ni)
        acc[mi][ni] += *(const f32x4*)(mb + (((mi * 8 + ni) << 6) + lane) * 16);
    // ---- epilogue: C/D layout col=lane&15, row=(lane>>4)*4+q (proven) ----
    const float blo = bias[lane & 15];
    const float bhi = bias[(lane & 15) + 16];
#pragma unroll
    for (int mi = 0; mi < 4; ++mi) {
#pragma unroll
      for (int ni = 0; ni < 8; ++ni) {
        const float badd = (ni & 1) ? bhi : blo;
#pragma unroll
        for (int q = 0; q < 4; ++q) {
          const int n = rowoff + bm0 + wr * 64 + mi * 16 + ((lane >> 4) << 2) + q;
          const int cidx = bn0 + ni * 16 + (lane & 15);
          const int bb = cidx >> 5;
          const int o = cidx & 31;
          out[(((size_t)bb << 12) + n) * 32 + o] = acc[mi][ni][q] + badd;
        }
      }
    }
  }
}

extern "C" void kernel_launch(void* const* d_in, const int* in_sizes, int n_in,
                              void* d_out, int out_size, void* d_ws, size_t ws_size,
                              hipStream_t stream) {
  const float* x = (const float*)d_in[0];
  const float* adj = (const float*)d_in[1];
  const float* W = (const float*)d_in[2];
  const float* bias = (const float*)d_in[3];
  float* out = (float*)d_out;

  const size_t ST_B = (size_t)2048 * 4096 * 2;      // 16,777,216
  const size_t ADJ_FULL = (size_t)4096 * 4096 * 2;  // 33,554,432

  unsigned short* St = (unsigned short*)d_ws;

  if (ws_size >= ST_B + ADJ_FULL) {
    // full path (proven to run): fused prep + one GEMM (grid 512 = 2 blk/CU)
    unsigned short* adjB = St + (ST_B / 2);
    hipLaunchKernelGGL(k_prep, dim3(9216), dim3(256), 0, stream, x, adj, W, St,
                       adjB);
    hipLaunchKernelGGL(k_gemm6, dim3(512), dim3(256), 0, stream, adjB, St, bias,
                       out, 4, 0);
  } else {
    // fallback half-split (not expected to run): one 2048-row panel reused
    unsigned short* adjH = St + (ST_B / 2);
    hipLaunchKernelGGL(k_support, dim3((B_SZ * N_SZ) / 256), dim3(256), 0,
                       stream, x, W, St);
    hipLaunchKernelGGL(k_cvt, dim3((2048 * 4096) / 2048), dim3(256), 0, stream,
                       adj, adjH);
    hipLaunchKernelGGL(k_gemm6, dim3(256), dim3(256), 0, stream, adjH, St, bias,
                       out, 2, 0);
    hipLaunchKernelGGL(k_cvt, dim3((2048 * 4096) / 2048), dim3(256), 0, stream,
                       adj + (size_t)2048 * 4096, adjH);
    hipLaunchKernelGGL(k_gemm6, dim3(256), dim3(256), 0, stream, adjH, St, bias,
                       out, 2, 2048);
  }
}